// Round 4
// baseline (36672.723 us; speedup 1.0000x reference)
//
#include <hip/hip_runtime.h>

#define L 64
#define TLEN 200000
#define CH 528                        // divisible by 8; checkpoint cadence
#define NCH 379                       // ceil(200000/528); 378*528 = 199584
#define LASTLEN (TLEN - (NCH - 1) * CH)   // 416 (divisible by 8)
#define NEGV -10000.0f
#define STARTT 62
#define STOPT 63

// workspace layout (bytes) — total 123052 < 126940 proven available
#define CKPT_OFF 0                          // float[(NCH+1)*L]  = 97280 B
#define M_OFF ((NCH + 1) * L * 4)           // uchar[NCH*L]      = 24256 B
#define ETAG_OFF (M_OFF + NCH * L)          // int[NCH]          = 1516 B

typedef float f32x4 __attribute__((ext_vector_type(4)));

// Per-step barrier WITHOUT lgkmcnt drain — validated in round 3 (absmax 0.0):
// LDS ops issued pre-barrier are serviced before post-barrier reads arrive at
// the (near-empty) DS pipe. Plain ds_writes used here complete faster than
// the RMW atomics the hypothesis was validated with.
#define FAST_BARRIER() __asm__ volatile("s_barrier" ::: "memory")
#define STEP_BARRIER() __asm__ volatile("" ::: "memory")

// force v_max3_f32 (3-input max, 1 instruction); max is order-invariant over
// finite floats so every tree below is bit-identical to pairwise fmax.
__device__ __forceinline__ float max3f(float a, float b, float c) {
    float r;
    __asm__("v_max3_f32 %0, %1, %2, %3" : "=v"(r) : "v"(a), "v"(b), "v"(c));
    return r;
}

#define RL(v, k) __int_as_float(__builtin_amdgcn_readlane(__float_as_int(v), k))

// ---------------------------------------------------------------------------
// Pass 1: exact sequential forward recurrence (the critical path).
// 4 waves (256 threads), p-split: wave w owns prev-tags [16w,16w+16).
// ONE LDS round-trip per step (round-3 post-mortem: the atomic-combine path
// carried two LDS service latencies — read + RMW — plus reset traffic):
//   (E) each wave computes its 16-prev partial max pm_w[n] for all 64 n from
//       SGPR-broadcast v values (16 v_readlane of the previous combine —
//       register-file path, no LDS) and writes pm[n][w] with a plain
//       ds_write_b32 (bank-deswizzled by component: max is permutation-
//       invariant, so the reader never needs to unswizzle).
//   (A) after the barrier, lane l combines: one broadcast ds_read_b128 of
//       pm[p][0..3] for p = 16w + (l&15), max of 4 components, + feat[t][p]
//       (prefetched with permuted per-lane addressing) -> v_t[p] in-register.
// Bit-exactness: RN(max_w pm_w + f) == max_w RN(pm_w + f) (RN monotone), the
// component permutation only reorders a max, and each score is one
// RN(v[p]+T[n][p]) — identical to the reference recurrence. Checkpoints
// match bit-for-bit; replay kernels are unchanged.
// ---------------------------------------------------------------------------
__global__ __launch_bounds__(256, 1) void k_forward(const float* __restrict__ feats,
                                                    const float* __restrict__ trans,
                                                    float* __restrict__ ckpt) {
    const int tid = threadIdx.x;
    const int l = tid & 63;   // lane; also dest-tag n for the partial compute
    const int w = tid >> 6;   // wave id = prev-slice
    const int n = l;
    const int pcol = 16 * w + (l & 15);        // prev-tag this lane combines
    const int wswz = (w + (n >> 2)) & 3;       // write-component swizzle (4-way not 8-way banks)

    // T[n][16w .. 16w+16) — 4 quads; pin keeps them VGPR-resident (round-0
    // proven pattern; round-1 showed 16 quads/lane does NOT allocate).
    const f32x4* t4 = reinterpret_cast<const f32x4*>(trans) + n * 16 + w * 4;
    f32x4 q0 = t4[0], q1 = t4[1], q2 = t4[2], q3 = t4[3];
    __asm__ volatile("" : "+v"(q0), "+v"(q1), "+v"(q2), "+v"(q3));

    // pm[buf][p][component] — component holds wave (w' s.t. (w'+(p>>2))&3 == comp)
    __shared__ __align__(16) float pm[2][L][4];

    // v_{-1}[pcol] directly in-register (combined form)
    float vcomb = (pcol == STARTT) ? 0.0f : NEGV;

    // feat prefetch, permuted addressing: lane needs feats[t][pcol]
    float fc[8];
#pragma unroll
    for (int j = 0; j < 8; ++j) fc[j] = feats[j * L + pcol];

    int nextck = 0, cidx = 0;

#define FWD_STEP(BUF, FEAT)                                                    \
    do {                                                                       \
        /* (D) broadcast previous combine via register file */                 \
        const float s0 = RL(vcomb, 0),  s1 = RL(vcomb, 1);                     \
        const float s2 = RL(vcomb, 2),  s3 = RL(vcomb, 3);                     \
        const float s4 = RL(vcomb, 4),  s5 = RL(vcomb, 5);                     \
        const float s6 = RL(vcomb, 6),  s7 = RL(vcomb, 7);                     \
        const float s8 = RL(vcomb, 8),  s9 = RL(vcomb, 9);                     \
        const float s10 = RL(vcomb, 10), s11 = RL(vcomb, 11);                  \
        const float s12 = RL(vcomb, 12), s13 = RL(vcomb, 13);                  \
        const float s14 = RL(vcomb, 14), s15 = RL(vcomb, 15);                  \
        /* (E) partial max over this wave's 16 prevs for dest n */             \
        const float c0 = s0 + q0.x,  c1 = s1 + q0.y;                           \
        const float c2 = s2 + q0.z,  c3 = s3 + q0.w;                           \
        const float c4 = s4 + q1.x,  c5 = s5 + q1.y;                           \
        const float c6 = s6 + q1.z,  c7 = s7 + q1.w;                           \
        const float c8 = s8 + q2.x,  c9 = s9 + q2.y;                           \
        const float c10 = s10 + q2.z, c11 = s11 + q2.w;                        \
        const float c12 = s12 + q3.x, c13 = s13 + q3.y;                        \
        const float c14 = s14 + q3.z, c15 = s15 + q3.w;                        \
        const float a0 = max3f(c0, c1, c2);                                    \
        const float a1 = max3f(c3, c4, c5);                                    \
        const float a2 = max3f(c6, c7, c8);                                    \
        const float a3 = max3f(c9, c10, c11);                                  \
        const float a4 = max3f(c12, c13, c14);                                 \
        const float pmv = fmaxf(max3f(a0, a1, a2), max3f(a3, a4, c15));        \
        /* (F) plain write — no RMW, no reset */                               \
        pm[BUF][n][wswz] = pmv;                                                \
        FAST_BARRIER();                                                        \
        /* (A) one broadcast b128 read + 4-way combine + feat */               \
        const f32x4 pq = *reinterpret_cast<const f32x4*>(&pm[BUF][pcol][0]);   \
        vcomb = fmaxf(max3f(pq.x, pq.y, pq.z), pq.w) + (FEAT);                 \
    } while (0)

    for (int tb = 0; tb < TLEN; tb += 8) {
        if (tb == nextck) {
            // vcomb holds v_{tb-1}[pcol]; lanes l<16 cover the wave's slice
            if (l < 16) ckpt[cidx * L + 16 * w + l] = vcomb;
            nextck += CH;
            ++cidx;
        }
        float fn_[8];
        const bool more = (tb + 8) < TLEN;
        if (more) {
#pragma unroll
            for (int j = 0; j < 8; ++j) fn_[j] = feats[(tb + 8 + j) * L + pcol];
        }
        FWD_STEP(0, fc[0]);
        FWD_STEP(1, fc[1]);
        FWD_STEP(0, fc[2]);
        FWD_STEP(1, fc[3]);
        FWD_STEP(0, fc[4]);
        FWD_STEP(1, fc[5]);
        FWD_STEP(0, fc[6]);
        FWD_STEP(1, fc[7]);
        if (more) {
#pragma unroll
            for (int j = 0; j < 8; ++j) fc[j] = fn_[j];
        }
    }
    // vcomb = v_{199999}[pcol]
    if (l < 16) ckpt[NCH * L + 16 * w + l] = vcomb;
#undef FWD_STEP
}

// ---------------------------------------------------------------------------
// helpers for the replay kernels (off the critical path, ~0.8 ms total)
// ---------------------------------------------------------------------------
__device__ __forceinline__ void load_trow(const float* __restrict__ trans, int n, float* trow) {
#pragma unroll
    for (int i = 0; i < 16; ++i) {
        const f32x4 q = reinterpret_cast<const f32x4*>(trans)[n * 16 + i];
        trow[4 * i + 0] = q.x;
        trow[4 * i + 1] = q.y;
        trow[4 * i + 2] = q.z;
        trow[4 * i + 3] = q.w;
    }
}

// Bit-exact chunk replay from checkpoint; records backpointers into LDS.
// Single wave per block; in-order DS pipe makes ds_write->ds_read safe with
// only a compiler barrier. Argmax is an in-order strictly-greater scan =>
// first-max, matching jnp.argmax; v matches k_forward bit-for-bit (max is
// order-invariant, +feat monotone-exact).
__device__ __forceinline__ void replay_chunk(const float* __restrict__ feats,
                                             const float* __restrict__ ckpt,
                                             const float* trow, float* vsh,
                                             unsigned char* bpl, int c, int len, int n) {
    float vreg = ckpt[c * L + n];
    vsh[n] = vreg;
    STEP_BARRIER();
    const int base = c * CH;

    float fc[8];
#pragma unroll
    for (int j = 0; j < 8; ++j) fc[j] = feats[(base + j) * L + n];

    for (int sb = 0; sb < len; sb += 8) {
        float fn_[8];
        const bool more = (sb + 8) < len;
        if (more) {
#pragma unroll
            for (int j = 0; j < 8; ++j) fn_[j] = feats[(base + sb + 8 + j) * L + n];
        }
#pragma unroll
        for (int j = 0; j < 8; ++j) {
            float mc[4];
            int ic[4];
#pragma unroll
            for (int g = 0; g < 4; ++g) {
                float m = -INFINITY;
                int idx = g * 16;
#pragma unroll
                for (int r = 0; r < 4; ++r) {
                    const int pb = g * 16 + r * 4;
                    const f32x4 vv = *reinterpret_cast<const f32x4*>(vsh + pb);
                    const float a = vv.x + trow[pb + 0];
                    const float b = vv.y + trow[pb + 1];
                    const float cc = vv.z + trow[pb + 2];
                    const float d = vv.w + trow[pb + 3];
                    if (a > m)  { m = a;  idx = pb + 0; }
                    if (b > m)  { m = b;  idx = pb + 1; }
                    if (cc > m) { m = cc; idx = pb + 2; }
                    if (d > m)  { m = d;  idx = pb + 3; }
                }
                mc[g] = m;
                ic[g] = idx;
            }
            float m = mc[0];
            int idx = ic[0];
            if (mc[1] > m) { m = mc[1]; idx = ic[1]; }
            if (mc[2] > m) { m = mc[2]; idx = ic[2]; }
            if (mc[3] > m) { m = mc[3]; idx = ic[3]; }

            vreg = m + fc[j];
            bpl[(sb + j) * L + n] = (unsigned char)idx;
            vsh[n] = vreg;
            STEP_BARRIER();
        }
        if (more) {
#pragma unroll
            for (int j = 0; j < 8; ++j) fc[j] = fn_[j];
        }
    }
}

// ---------------------------------------------------------------------------
// Pass 2: per-chunk bit-exact replay -> backpointers -> 64-entry chunk map.
// M[c*64+e] = tag at (c*CH - 1) given tag e at the last step of chunk c.
// ---------------------------------------------------------------------------
__global__ __launch_bounds__(64, 1) void k_maps(const float* __restrict__ feats,
                                                const float* __restrict__ trans,
                                                const float* __restrict__ ckpt,
                                                unsigned char* __restrict__ M) {
    const int c = blockIdx.x;
    const int n = threadIdx.x;
    const int len = (c == NCH - 1) ? LASTLEN : CH;

    __shared__ __align__(16) float vsh[L];
    __shared__ unsigned char bpl[CH * L];

    float trow[L];
    load_trow(trans, n, trow);
    replay_chunk(feats, ckpt, trow, vsh, bpl, c, len, n);
    __syncthreads();

    int tag = n;
    for (int s = len - 1; s >= 0; --s) tag = bpl[s * L + tag];
    M[c * L + n] = (unsigned char)tag;
}

// ---------------------------------------------------------------------------
// Pass 3: terminal argmax (bit-exact score) + back-to-front map composition.
// ---------------------------------------------------------------------------
__global__ __launch_bounds__(64, 1) void k_stitch(const float* __restrict__ trans,
                                                  const float* __restrict__ ckpt,
                                                  const unsigned char* __restrict__ M,
                                                  int* __restrict__ etag,
                                                  float* __restrict__ out) {
    const int n = threadIdx.x;
    __shared__ float tsh[L];
    __shared__ int bsh;
    __shared__ __align__(16) unsigned char msh[NCH * L];

    tsh[n] = ckpt[NCH * L + n] + trans[STOPT * L + n];  // terminal[n]
    __syncthreads();
    if (n == 0) {
        float m = tsh[0];
        int b = 0;
        for (int p = 1; p < L; ++p)
            if (tsh[p] > m) { m = tsh[p]; b = p; }  // first-max, like jnp.argmax
        out[0] = m;   // path_score, bit-exact
        bsh = b;
    }
    __syncthreads();

    for (int i = n; i < (NCH * L) / 4; i += L)
        reinterpret_cast<int*>(msh)[i] = reinterpret_cast<const int*>(M)[i];
    __syncthreads();

    if (n == 0) {
        int carry = bsh;  // tag at t = T-1 = end of chunk NCH-1
        for (int c = NCH - 1; c >= 1; --c) {
            etag[c] = carry;
            carry = msh[c * L + carry];
        }
        etag[0] = carry;
    }
}

// ---------------------------------------------------------------------------
// Pass 4: per-chunk replay again, walk backwards from etag[c], emit path.
// Path written as float32 (harness reads the concatenated output as float).
// ---------------------------------------------------------------------------
__global__ __launch_bounds__(64, 1) void k_emit(const float* __restrict__ feats,
                                                const float* __restrict__ trans,
                                                const float* __restrict__ ckpt,
                                                const int* __restrict__ etag,
                                                float* __restrict__ out) {
    const int c = blockIdx.x;
    const int n = threadIdx.x;
    const int len = (c == NCH - 1) ? LASTLEN : CH;

    __shared__ __align__(16) float vsh[L];
    __shared__ unsigned char bpl[CH * L];
    __shared__ unsigned char plc[CH];

    float trow[L];
    load_trow(trans, n, trow);
    replay_chunk(feats, ckpt, trow, vsh, bpl, c, len, n);
    __syncthreads();

    int tag = etag[c];  // uniform; bpl reads below broadcast (same address)
    for (int s = len - 1; s >= 0; --s) {
        if (n == 0) plc[s] = (unsigned char)tag;
        tag = bpl[s * L + tag];
    }
    __syncthreads();

    for (int i = n; i < len; i += L)
        out[1 + c * CH + i] = (float)plc[i];
}

// ---------------------------------------------------------------------------
extern "C" void kernel_launch(void* const* d_in, const int* in_sizes, int n_in,
                              void* d_out, int out_size, void* d_ws, size_t ws_size,
                              hipStream_t stream) {
    const float* feats = (const float*)d_in[0];   // (1, T, L) fp32
    const float* trans = (const float*)d_in[1];   // (L, L) fp32
    float* out = (float*)d_out;                   // [score, path(T) as float]
    char* ws = (char*)d_ws;
    float* ckpt = (float*)(ws + CKPT_OFF);
    unsigned char* M = (unsigned char*)(ws + M_OFF);
    int* etag = (int*)(ws + ETAG_OFF);

    hipLaunchKernelGGL(k_forward, dim3(1), dim3(256), 0, stream, feats, trans, ckpt);
    hipLaunchKernelGGL(k_maps, dim3(NCH), dim3(64), 0, stream, feats, trans, ckpt, M);
    hipLaunchKernelGGL(k_stitch, dim3(1), dim3(64), 0, stream, trans, ckpt, M, etag, out);
    hipLaunchKernelGGL(k_emit, dim3(NCH), dim3(64), 0, stream, feats, trans, ckpt, etag, out);
}